// Round 4
// baseline (210.183 us; speedup 1.0000x reference)
//
#include <hip/hip_runtime.h>
#include <math.h>

#define NCn 64            // chunks per batch
#define NCHUNK 256        // total chunks (B=4)

__device__ __forceinline__ float elu1(float v) {
    return (v > 0.f) ? v + 1.f : expf(v);
}

// ---------------------------------------------------------------------------
// Kernel AB: per chunk (32 rows):
//   qkv = x @ W^T + b (elu+1 on q,k) ; K^T V ; ksum ; causal QK^T + rowsum
// grid 256 x 384 threads.
// Phase 1: GEMM, thread = 16 rows x 2 cols (c0, c0+192); W staged transposed
//          sWt[k][c] (stride 385) per 32-k chunk; coalesced global reads,
//          ~2-way LDS write banks, conflict-free lane-consecutive reads.
// Phase 2: tid<256: K^T V 8x8 tiles; tid>=256: scores 2t x 4tp f4-dots.
// ---------------------------------------------------------------------------
__global__ __launch_bounds__(384) void ab_kernel(
    const float* __restrict__ x, const float* __restrict__ W,
    const float* __restrict__ bias,
    float* __restrict__ qb, float* __restrict__ vb,
    float* __restrict__ kvb, float* __restrict__ ksb,
    float* __restrict__ scb, float* __restrict__ rsb)
{
    __shared__ __align__(16) float xs[32 * 128];
    __shared__ __align__(16) float sWt[32 * 385];
    __shared__ __align__(16) float sQ[32 * 132];
    __shared__ __align__(16) float sK[32 * 132];
    __shared__ __align__(16) float sV[32 * 132];
    __shared__ __align__(16) float sSc[32 * 36];

    const int tid = threadIdx.x;
    const int cb = blockIdx.x;

    // stage x chunk (32x128) as float4
    {
        const float4* xg = (const float4*)(x + (size_t)cb * 4096);
        float4* xls = (float4*)xs;
        for (int idx = tid; idx < 1024; idx += 384) xls[idx] = xg[idx];
    }

    const int rh = tid / 192;          // 0..1 -> rows rh*16..rh*16+15
    const int c0 = tid % 192;          // this thread's cols: c0, c0+192
    const int c1 = c0 + 192;

    float acc0[16], acc1[16];
#pragma unroll
    for (int r = 0; r < 16; ++r) { acc0[r] = 0.f; acc1[r] = 0.f; }

    const float4* W4 = (const float4*)W;   // row c = 32 float4
    for (int kc = 0; kc < 4; ++kc) {
        __syncthreads();   // xs ready (kc=0); prior-iter sWt readers done
        // stage W[:, kc*32..+32) transposed: coalesced reads, scatter writes
#pragma unroll
        for (int p = 0; p < 8; ++p) {
            const int flat = tid + p * 384;      // 0..3071
            const int c = flat >> 3, f = flat & 7;
            float4 w = W4[c * 32 + kc * 8 + f];
            sWt[(f * 4 + 0) * 385 + c] = w.x;
            sWt[(f * 4 + 1) * 385 + c] = w.y;
            sWt[(f * 4 + 2) * 385 + c] = w.z;
            sWt[(f * 4 + 3) * 385 + c] = w.w;
        }
        __syncthreads();
#pragma unroll
        for (int k4 = 0; k4 < 8; ++k4) {
            const float w00 = sWt[(k4*4+0)*385 + c0];
            const float w01 = sWt[(k4*4+1)*385 + c0];
            const float w02 = sWt[(k4*4+2)*385 + c0];
            const float w03 = sWt[(k4*4+3)*385 + c0];
            const float w10 = sWt[(k4*4+0)*385 + c1];
            const float w11 = sWt[(k4*4+1)*385 + c1];
            const float w12 = sWt[(k4*4+2)*385 + c1];
            const float w13 = sWt[(k4*4+3)*385 + c1];
#pragma unroll
            for (int r = 0; r < 16; ++r) {
                float4 xv = *(const float4*)&xs[(rh*16+r)*128 + kc*32 + k4*4];
                acc0[r] += xv.x*w00 + xv.y*w01 + xv.z*w02 + xv.w*w03;
                acc1[r] += xv.x*w10 + xv.y*w11 + xv.z*w12 + xv.w*w13;
            }
        }
    }

    // phase-1 epilogue: bias + activation -> sQ/sK/sV
    {
        const float bb0 = bias[c0], bb1 = bias[c1];
#pragma unroll
        for (int r = 0; r < 16; ++r) {
            const int row = rh*16 + r;
            float v0 = acc0[r] + bb0;
            float v1 = acc1[r] + bb1;
            if (c0 < 128) sQ[row*132 + c0]         = elu1(v0);
            else          sK[row*132 + (c0 - 128)] = elu1(v0);
            if (c1 < 256) sK[row*132 + (c1 - 128)] = elu1(v1);
            else          sV[row*132 + (c1 - 256)] = v1;
        }
    }
    __syncthreads();

    // copy q, v to global (row-major, coalesced f4)
    {
        float4* qg = (float4*)(qb + (size_t)cb * 4096);
        float4* vg = (float4*)(vb + (size_t)cb * 4096);
        for (int idx = tid; idx < 1024; idx += 384) {
            int t = idx >> 5, c4 = idx & 31;
            qg[idx] = *(const float4*)&sQ[t*132 + c4*4];
            vg[idx] = *(const float4*)&sV[t*132 + c4*4];
        }
    }

    if (tid < 256) {
        // K^T V : 128x128, 8x8 register tile
        const int i0 = (tid >> 4) * 8, j0 = (tid & 15) * 8;
        float acc[8][8];
#pragma unroll
        for (int a = 0; a < 8; ++a)
#pragma unroll
            for (int b2 = 0; b2 < 8; ++b2) acc[a][b2] = 0.f;
#pragma unroll 2
        for (int t = 0; t < 32; ++t) {
            float4 ka  = *(const float4*)&sK[t*132 + i0];
            float4 kb4 = *(const float4*)&sK[t*132 + i0 + 4];
            float4 va  = *(const float4*)&sV[t*132 + j0];
            float4 vb4 = *(const float4*)&sV[t*132 + j0 + 4];
            float kk[8] = {ka.x, ka.y, ka.z, ka.w, kb4.x, kb4.y, kb4.z, kb4.w};
            float vv[8] = {va.x, va.y, va.z, va.w, vb4.x, vb4.y, vb4.z, vb4.w};
#pragma unroll
            for (int a = 0; a < 8; ++a)
#pragma unroll
                for (int b2 = 0; b2 < 8; ++b2) acc[a][b2] += kk[a] * vv[b2];
        }
        float* outp = kvb + (size_t)cb * 16384;
#pragma unroll
        for (int a = 0; a < 8; ++a) {
            *(float4*)&outp[(i0+a)*128 + j0] =
                make_float4(acc[a][0], acc[a][1], acc[a][2], acc[a][3]);
            *(float4*)&outp[(i0+a)*128 + j0 + 4] =
                make_float4(acc[a][4], acc[a][5], acc[a][6], acc[a][7]);
        }
    } else {
        // causal scores: sid -> t in {ta, ta+16}, tp0..tp0+3
        const int sid = tid - 256;
        const int ta  = sid >> 3;
        const int tp0 = (sid & 7) * 4;
        float d0[4] = {0.f,0.f,0.f,0.f}, d1[4] = {0.f,0.f,0.f,0.f};
#pragma unroll 4
        for (int k4 = 0; k4 < 32; ++k4) {
            float4 qa = *(const float4*)&sQ[ta*132 + k4*4];
            float4 qc = *(const float4*)&sQ[(ta+16)*132 + k4*4];
#pragma unroll
            for (int u = 0; u < 4; ++u) {
                float4 kv = *(const float4*)&sK[(tp0+u)*132 + k4*4];
                d0[u] += qa.x*kv.x + qa.y*kv.y + qa.z*kv.z + qa.w*kv.w;
                d1[u] += qc.x*kv.x + qc.y*kv.y + qc.z*kv.z + qc.w*kv.w;
            }
        }
        float4 m0, m1;
        m0.x = (tp0+0 <= ta) ? d0[0] : 0.f;
        m0.y = (tp0+1 <= ta) ? d0[1] : 0.f;
        m0.z = (tp0+2 <= ta) ? d0[2] : 0.f;
        m0.w = (tp0+3 <= ta) ? d0[3] : 0.f;
        m1.x = (tp0+0 <= ta+16) ? d1[0] : 0.f;
        m1.y = (tp0+1 <= ta+16) ? d1[1] : 0.f;
        m1.z = (tp0+2 <= ta+16) ? d1[2] : 0.f;
        m1.w = (tp0+3 <= ta+16) ? d1[3] : 0.f;
        *(float4*)&sSc[ta*36 + tp0]      = m0;
        *(float4*)&sSc[(ta+16)*36 + tp0] = m1;
        float4* sg = (float4*)(scb + (size_t)cb * 1024);
        sg[ta*8 + (sid & 7)]      = m0;
        sg[(ta+16)*8 + (sid & 7)] = m1;
    }
    __syncthreads();

    if (tid < 128) {                 // ksum: colsum(K)
        float s = 0.f;
#pragma unroll
        for (int t = 0; t < 32; ++t) s += sK[t*132 + tid];
        ksb[cb*128 + tid] = s;
    } else if (tid < 160) {          // rowsum of masked scores
        const int t = tid - 128;
        float s = 0.f;
#pragma unroll
        for (int tp = 0; tp < 32; ++tp) s += sSc[t*36 + tp];
        rsb[cb*32 + t] = s;
    }
}

// ---------------------------------------------------------------------------
// Kernel C: in-place exclusive prefix over 64 chunks per batch (kvb, ksb).
// Scalar coalesced lines; 16-deep load batching. grid 258 x 256.
// ---------------------------------------------------------------------------
__global__ __launch_bounds__(256) void prefix_kernel(
    float* __restrict__ kvb, float* __restrict__ ksb)
{
    const int tid = threadIdx.x;
    if (blockIdx.x < 256) {
        const int L = blockIdx.x * 256 + tid;      // (b, ij)
        const int b = L >> 14, ij = L & 16383;
        float* p = kvb + (size_t)b * NCn * 16384 + ij;
        float run = 0.f;
        for (int g = 0; g < 4; ++g) {
            float buf[16];
#pragma unroll
            for (int j = 0; j < 16; ++j) buf[j] = p[(size_t)(g*16 + j) * 16384];
#pragma unroll
            for (int j = 0; j < 16; ++j) {
                p[(size_t)(g*16 + j) * 16384] = run;
                run += buf[j];
            }
        }
    } else {
        const int L = (blockIdx.x - 256) * 256 + tid;  // (b, i)
        const int b = L >> 7, i = L & 127;
        float* p = ksb + (size_t)b * NCn * 128 + i;
        float run = 0.f;
        for (int g = 0; g < 4; ++g) {
            float buf[16];
#pragma unroll
            for (int j = 0; j < 16; ++j) buf[j] = p[(size_t)(g*16 + j) * 128];
#pragma unroll
            for (int j = 0; j < 16; ++j) {
                p[(size_t)(g*16 + j) * 128] = run;
                run += buf[j];
            }
        }
    }
}

// ---------------------------------------------------------------------------
// Kernel D: out = (Q @ S_prefix + Sc @ V) / den ; den = Q.kpre + rowsumSc + eps
// grid 256 x 256; thread = 4 rows x 4 cols, row-major f4 reads (VALU-bound).
// ---------------------------------------------------------------------------
__global__ __launch_bounds__(256) void out_kernel(
    const float* __restrict__ qb, const float* __restrict__ vb,
    const float* __restrict__ kvb, const float* __restrict__ ksb,
    const float* __restrict__ scb, const float* __restrict__ rsb,
    float* __restrict__ out)
{
    __shared__ __align__(16) float sS[128 * 128];
    __shared__ __align__(16) float sQ[32 * 132];
    __shared__ __align__(16) float sV[32 * 132];
    __shared__ __align__(16) float sSc[32 * 36];
    __shared__ __align__(16) float sKp[128];
    __shared__ float sDen[32];

    const int tid = threadIdx.x;
    const int cb = blockIdx.x;

    {
        const float4* gS = (const float4*)(kvb + (size_t)cb * 16384);
        float4* sS4 = (float4*)sS;
#pragma unroll
        for (int j = 0; j < 16; ++j) sS4[tid + j*256] = gS[tid + j*256];
        const float4* qg = (const float4*)(qb + (size_t)cb * 4096);
        const float4* vg = (const float4*)(vb + (size_t)cb * 4096);
#pragma unroll
        for (int j = 0; j < 4; ++j) {
            int idx = tid + j*256;
            int t = idx >> 5, c4 = idx & 31;
            *(float4*)&sQ[t*132 + c4*4] = qg[idx];
            *(float4*)&sV[t*132 + c4*4] = vg[idx];
        }
        const float4* sg = (const float4*)(scb + (size_t)cb * 1024);
        int t = tid >> 3, p4 = tid & 7;
        *(float4*)&sSc[t*36 + p4*4] = sg[tid];
        if (tid < 128) sKp[tid] = ksb[cb*128 + tid];
    }
    __syncthreads();

    if (tid < 32) {      // den
        float d = 0.f;
#pragma unroll
        for (int k4 = 0; k4 < 32; ++k4) {
            float4 a  = *(const float4*)&sQ[tid*132 + k4*4];
            float4 b2 = *(const float4*)&sKp[k4*4];
            d += a.x*b2.x + a.y*b2.y + a.z*b2.z + a.w*b2.w;
        }
        sDen[tid] = d + rsb[cb*32 + tid] + 1e-6f;
    }

    const int r0 = (tid >> 5) * 4;
    const int c0 = (tid & 31) * 4;
    float acc[4][4];
#pragma unroll
    for (int a = 0; a < 4; ++a)
#pragma unroll
        for (int b2 = 0; b2 < 4; ++b2) acc[a][b2] = 0.f;

    // inter: Q @ S_prefix
    for (int k4 = 0; k4 < 32; ++k4) {
        float qr[4][4];
#pragma unroll
        for (int rr = 0; rr < 4; ++rr) {
            float4 t4 = *(const float4*)&sQ[(r0+rr)*132 + k4*4];
            qr[rr][0]=t4.x; qr[rr][1]=t4.y; qr[rr][2]=t4.z; qr[rr][3]=t4.w;
        }
#pragma unroll
        for (int u = 0; u < 4; ++u) {
            float4 s4 = *(const float4*)&sS[(k4*4+u)*128 + c0];
#pragma unroll
            for (int rr = 0; rr < 4; ++rr) {
                acc[rr][0] += qr[rr][u]*s4.x;
                acc[rr][1] += qr[rr][u]*s4.y;
                acc[rr][2] += qr[rr][u]*s4.z;
                acc[rr][3] += qr[rr][u]*s4.w;
            }
        }
    }

    // intra: Sc @ V (masked zeros keep it uniform)
#pragma unroll
    for (int p4 = 0; p4 < 8; ++p4) {
        float sr[4][4];
#pragma unroll
        for (int rr = 0; rr < 4; ++rr) {
            float4 t4 = *(const float4*)&sSc[(r0+rr)*36 + p4*4];
            sr[rr][0]=t4.x; sr[rr][1]=t4.y; sr[rr][2]=t4.z; sr[rr][3]=t4.w;
        }
#pragma unroll
        for (int u = 0; u < 4; ++u) {
            float4 v4 = *(const float4*)&sV[(p4*4+u)*132 + c0];
#pragma unroll
            for (int rr = 0; rr < 4; ++rr) {
                acc[rr][0] += sr[rr][u]*v4.x;
                acc[rr][1] += sr[rr][u]*v4.y;
                acc[rr][2] += sr[rr][u]*v4.z;
                acc[rr][3] += sr[rr][u]*v4.w;
            }
        }
    }
    __syncthreads();   // sDen visible

#pragma unroll
    for (int rr = 0; rr < 4; ++rr) {
        const float dv = sDen[r0+rr];
        *(float4*)(out + ((size_t)cb*32 + r0+rr)*128 + c0) =
            make_float4(acc[rr][0]/dv, acc[rr][1]/dv, acc[rr][2]/dv, acc[rr][3]/dv);
    }
}

// ---------------------------------------------------------------------------
extern "C" void kernel_launch(void* const* d_in, const int* in_sizes, int n_in,
                              void* d_out, int out_size, void* d_ws, size_t ws_size,
                              hipStream_t stream)
{
    const float* x    = (const float*)d_in[0];   // (B,T,D)
    const float* W    = (const float*)d_in[1];   // (3D, D)
    const float* bias = (const float*)d_in[2];   // (3D,)
    float* out = (float*)d_out;                  // (B,T,D)

    float* ws  = (float*)d_ws;
    float* qb  = ws;                       // 1,048,576 floats
    float* vb  = ws + 1048576;             // 1,048,576
    float* kvb = ws + 2097152;             // 4,194,304
    float* ksb = ws + 6291456;             // 32,768
    float* scb = ws + 6324224;             // 262,144
    float* rsb = ws + 6586368;             // 8,192

    ab_kernel<<<NCHUNK, 384, 0, stream>>>(x, W, bias, qb, vb, kvb, ksb, scb, rsb);
    prefix_kernel<<<258, 256, 0, stream>>>(kvb, ksb);
    out_kernel<<<NCHUNK, 256, 0, stream>>>(qb, vb, kvb, ksb, scb, rsb, out);
}

// Round 5
// 133.267 us; speedup vs baseline: 1.5772x; 1.5772x over previous
//
#include <hip/hip_runtime.h>
#include <math.h>

#define NCn 64            // chunks per batch
#define NCHUNK 256        // total chunks (B=4)
#define NROW 8192         // B*T

__device__ __forceinline__ float elu1(float v) {
    return (v > 0.f) ? v + 1.f : expf(v);
}

// ---------------------------------------------------------------------------
// Kernel T: Wt[k][c] = W[c][k]   (384x128 -> 128x384), 32x32 LDS tiles
// ---------------------------------------------------------------------------
__global__ __launch_bounds__(256) void wt_kernel(
    const float* __restrict__ W, float* __restrict__ Wt)
{
    __shared__ float t[32][33];
    const int bi = blockIdx.x >> 2;      // c-tile 0..11
    const int bj = blockIdx.x & 3;       // k-tile 0..3
    const int r0 = bi * 32, c0 = bj * 32;
    const int tr = threadIdx.x >> 5, tc = threadIdx.x & 31;  // 8 x 32
#pragma unroll
    for (int rr = tr; rr < 32; rr += 8)
        t[rr][tc] = W[(r0 + rr) * 128 + c0 + tc];
    __syncthreads();
#pragma unroll
    for (int rr = tr; rr < 32; rr += 8)
        Wt[(c0 + rr) * 384 + r0 + tc] = t[tc][rr];
}

// ---------------------------------------------------------------------------
// Kernel A: qkv = x @ W^T + b ; q,k <- elu+1 ; split into q,k,v buffers
// grid 512 x 192; 16 rows/block; thread: cols (tid, tid+192) x 16 rows
// (unchanged from the measured 131.6us pipeline)
// ---------------------------------------------------------------------------
__global__ __launch_bounds__(192) void qkv_kernel(
    const float* __restrict__ x, const float* __restrict__ Wt,
    const float* __restrict__ bias, float* __restrict__ qb,
    float* __restrict__ kb, float* __restrict__ vb)
{
    __shared__ __align__(16) float xs[16 * 128];
    const int tid = threadIdx.x;
    const int row0 = blockIdx.x * 16;

    {
        const float4* xg = (const float4*)(x + (size_t)row0 * 128);
        float4* xls = (float4*)xs;
        for (int i = tid; i < 16 * 32; i += 192) xls[i] = xg[i];
    }
    __syncthreads();

    const int c0 = tid, c1 = tid + 192;
    float acc0[16], acc1[16];
#pragma unroll
    for (int r = 0; r < 16; ++r) { acc0[r] = 0.f; acc1[r] = 0.f; }

    for (int k4 = 0; k4 < 32; ++k4) {
        float w0[4], w1[4];
#pragma unroll
        for (int u = 0; u < 4; ++u) {
            w0[u] = Wt[(size_t)(k4 * 4 + u) * 384 + c0];
            w1[u] = Wt[(size_t)(k4 * 4 + u) * 384 + c1];
        }
        float4 xv[16];
#pragma unroll
        for (int r = 0; r < 16; ++r) xv[r] = *(const float4*)&xs[r * 128 + k4 * 4];
#pragma unroll
        for (int r = 0; r < 16; ++r) {
            acc0[r] += xv[r].x * w0[0] + xv[r].y * w0[1] + xv[r].z * w0[2] + xv[r].w * w0[3];
            acc1[r] += xv[r].x * w1[0] + xv[r].y * w1[1] + xv[r].z * w1[2] + xv[r].w * w1[3];
        }
    }

    const float bb0 = bias[c0], bb1 = bias[c1];
#pragma unroll
    for (int r = 0; r < 16; ++r) {
        const size_t row = (size_t)(row0 + r);
        float v0 = acc0[r] + bb0;
        float v1 = acc1[r] + bb1;
        if (c0 < 128) qb[row * 128 + c0] = elu1(v0);
        else          kb[row * 128 + (c0 - 128)] = elu1(v0);
        if (c1 < 256) kb[row * 128 + (c1 - 128)] = elu1(v1);
        else          vb[row * 128 + (c1 - 256)] = v1;
    }
}

// ---------------------------------------------------------------------------
// Kernel CS: grid 768 x 256, LDS 38.4 KB -> 3 blocks/CU.
//  blocks [0,512): half-K^T V. cb = b>>1, jh = b&1: 128 x 64 of kvb[cb].
//  blocks [512,768): scores. cb = b-512: causal QK^T (32x32) -> scb, sSc;
//                    rowsum -> rsb; colsum(K) -> ksb.
// ---------------------------------------------------------------------------
__global__ __launch_bounds__(256) void cs_kernel(
    const float* __restrict__ qb, const float* __restrict__ kb,
    const float* __restrict__ vb,
    float* __restrict__ kvb, float* __restrict__ ksb,
    float* __restrict__ scb, float* __restrict__ rsb)
{
    __shared__ __align__(16) float smem[9600];   // 38.4 KB
    const int tid = threadIdx.x;
    const int b = blockIdx.x;

    if (b < 512) {
        const int cb = b >> 1, jh = b & 1;
        float* sK  = smem;          // [32][132]
        float* sVh = smem + 4224;   // [32][68]
        {
            const float4* kg = (const float4*)(kb + (size_t)cb * 4096);
#pragma unroll
            for (int i = 0; i < 4; ++i) {
                int idx = tid + i * 256;            // 0..1023
                int r = idx >> 5, c4 = idx & 31;
                *(float4*)&sK[r * 132 + c4 * 4] = kg[idx];
            }
            const float* vg = vb + (size_t)cb * 4096 + jh * 64;
#pragma unroll
            for (int i = 0; i < 2; ++i) {
                int idx = tid + i * 256;            // 0..511
                int r = idx >> 4, c4 = idx & 15;
                *(float4*)&sVh[r * 68 + c4 * 4] = *(const float4*)(vg + r * 128 + c4 * 4);
            }
        }
        __syncthreads();

        const int i0 = (tid >> 4) * 8;      // 0..120
        const int j0 = (tid & 15) * 4;      // 0..60
        float acc[8][4];
#pragma unroll
        for (int a = 0; a < 8; ++a)
#pragma unroll
            for (int c = 0; c < 4; ++c) acc[a][c] = 0.f;

#pragma unroll 2
        for (int t = 0; t < 32; ++t) {
            float4 ka  = *(const float4*)&sK[t * 132 + i0];
            float4 kb4 = *(const float4*)&sK[t * 132 + i0 + 4];
            float4 vv  = *(const float4*)&sVh[t * 68 + j0];
            float kk[8] = {ka.x, ka.y, ka.z, ka.w, kb4.x, kb4.y, kb4.z, kb4.w};
#pragma unroll
            for (int a = 0; a < 8; ++a) {
                acc[a][0] += kk[a] * vv.x;
                acc[a][1] += kk[a] * vv.y;
                acc[a][2] += kk[a] * vv.z;
                acc[a][3] += kk[a] * vv.w;
            }
        }
        float* outp = kvb + (size_t)cb * 16384 + jh * 64;
#pragma unroll
        for (int a = 0; a < 8; ++a)
            *(float4*)&outp[(i0 + a) * 128 + j0] =
                make_float4(acc[a][0], acc[a][1], acc[a][2], acc[a][3]);
    } else {
        const int cb = b - 512;
        float* sQ  = smem;          // [32][132]
        float* sK2 = smem + 4224;   // [32][132]
        float* sSc = smem + 8448;   // [32][36]
        {
            const float4* qg = (const float4*)(qb + (size_t)cb * 4096);
            const float4* kg = (const float4*)(kb + (size_t)cb * 4096);
#pragma unroll
            for (int i = 0; i < 4; ++i) {
                int idx = tid + i * 256;
                int r = idx >> 5, c4 = idx & 31;
                *(float4*)&sQ[r * 132 + c4 * 4]  = qg[idx];
                *(float4*)&sK2[r * 132 + c4 * 4] = kg[idx];
            }
        }
        __syncthreads();

        const int ta  = tid >> 3;           // 0..31
        const int tp0 = (tid & 7) * 4;      // 0..28
        float d[4] = {0.f, 0.f, 0.f, 0.f};
#pragma unroll 4
        for (int k4 = 0; k4 < 32; ++k4) {
            float4 qa = *(const float4*)&sQ[ta * 132 + k4 * 4];
#pragma unroll
            for (int u = 0; u < 4; ++u) {
                float4 kv = *(const float4*)&sK2[(tp0 + u) * 132 + k4 * 4];
                d[u] += qa.x * kv.x + qa.y * kv.y + qa.z * kv.z + qa.w * kv.w;
            }
        }
        float4 m;
        m.x = (tp0 + 0 <= ta) ? d[0] : 0.f;
        m.y = (tp0 + 1 <= ta) ? d[1] : 0.f;
        m.z = (tp0 + 2 <= ta) ? d[2] : 0.f;
        m.w = (tp0 + 3 <= ta) ? d[3] : 0.f;
        *(float4*)&sSc[ta * 36 + tp0] = m;
        *(float4*)(scb + (size_t)cb * 1024 + ta * 32 + tp0) = m;
        __syncthreads();

        if (tid < 32) {              // rowsum of masked scores
            float s = 0.f;
#pragma unroll
            for (int tp = 0; tp < 32; ++tp) s += sSc[tid * 36 + tp];
            rsb[cb * 32 + tid] = s;
        } else if (tid >= 64 && tid < 192) {   // colsum(K)
            const int i = tid - 64;
            float s = 0.f;
#pragma unroll
            for (int t = 0; t < 32; ++t) s += sK2[t * 132 + i];
            ksb[cb * 128 + i] = s;
        }
    }
}

// ---------------------------------------------------------------------------
// Kernel C: in-place exclusive prefix over 64 chunks per batch (kvb, ksb).
// Scalar coalesced lines; 16-deep load batching. grid 258 x 256.
// ---------------------------------------------------------------------------
__global__ __launch_bounds__(256) void prefix_kernel(
    float* __restrict__ kvb, float* __restrict__ ksb)
{
    const int tid = threadIdx.x;
    if (blockIdx.x < 256) {
        const int L = blockIdx.x * 256 + tid;      // (b, ij)
        const int b = L >> 14, ij = L & 16383;
        float* p = kvb + (size_t)b * NCn * 16384 + ij;
        float run = 0.f;
        for (int g = 0; g < 4; ++g) {
            float buf[16];
#pragma unroll
            for (int j = 0; j < 16; ++j) buf[j] = p[(size_t)(g * 16 + j) * 16384];
#pragma unroll
            for (int j = 0; j < 16; ++j) {
                p[(size_t)(g * 16 + j) * 16384] = run;
                run += buf[j];
            }
        }
    } else {
        const int L = (blockIdx.x - 256) * 256 + tid;  // (b, i)
        const int b = L >> 7, i = L & 127;
        float* p = ksb + (size_t)b * NCn * 128 + i;
        float run = 0.f;
        for (int g = 0; g < 4; ++g) {
            float buf[16];
#pragma unroll
            for (int j = 0; j < 16; ++j) buf[j] = p[(size_t)(g * 16 + j) * 128];
#pragma unroll
            for (int j = 0; j < 16; ++j) {
                p[(size_t)(g * 16 + j) * 128] = run;
                run += buf[j];
            }
        }
    }
}

// ---------------------------------------------------------------------------
// Kernel D: out = (Q @ S_prefix + Sc @ V) / den
// grid 1024 x 256 (4 col-blocks per chunk), LDS 22.8 KB -> 4 blocks/CU.
// S streamed from global (L2/L3-resident); thread = 1 output float4.
// ---------------------------------------------------------------------------
__global__ __launch_bounds__(256) void out_kernel(
    const float* __restrict__ qb, const float* __restrict__ vb,
    const float* __restrict__ kvb, const float* __restrict__ ksb,
    const float* __restrict__ scb, const float* __restrict__ rsb,
    float* __restrict__ out)
{
    __shared__ __align__(16) float sQ[32 * 132];
    __shared__ __align__(16) float sVs[32 * 36];
    __shared__ __align__(16) float sSc[32 * 36];
    __shared__ __align__(16) float sKp[128];
    __shared__ float sDen[32];

    const int tid = threadIdx.x;
    const int cb = blockIdx.x >> 2;        // chunk
    const int ch = blockIdx.x & 3;         // 32-col slice

    {
        const float4* qg = (const float4*)(qb + (size_t)cb * 4096);
#pragma unroll
        for (int i = 0; i < 4; ++i) {
            int idx = tid + i * 256;
            int r = idx >> 5, c4 = idx & 31;
            *(float4*)&sQ[r * 132 + c4 * 4] = qg[idx];
        }
        {   // V slice [32][32]
            int r = tid >> 3, c4 = tid & 7;
            *(float4*)&sVs[r * 36 + c4 * 4] =
                *(const float4*)(vb + (size_t)cb * 4096 + r * 128 + ch * 32 + c4 * 4);
            *(float4*)&sSc[r * 36 + c4 * 4] =
                *(const float4*)(scb + (size_t)cb * 1024 + tid * 4);
        }
        if (tid < 128) sKp[tid] = ksb[cb * 128 + tid];
    }
    __syncthreads();

    if (tid < 32) {      // den
        float d = 0.f;
#pragma unroll
        for (int k4 = 0; k4 < 32; ++k4) {
            float4 a  = *(const float4*)&sQ[tid * 132 + k4 * 4];
            float4 b2 = *(const float4*)&sKp[k4 * 4];
            d += a.x * b2.x + a.y * b2.y + a.z * b2.z + a.w * b2.w;
        }
        sDen[tid] = d + rsb[cb * 32 + tid] + 1e-6f;
    }

    const int row = tid >> 3;              // 0..31
    const int c4  = tid & 7;               // 0..7
    const float* Sg = kvb + (size_t)cb * 16384 + ch * 32 + c4 * 4;

    float a0 = 0.f, a1 = 0.f, a2 = 0.f, a3 = 0.f;
#pragma unroll 8
    for (int k = 0; k < 128; ++k) {
        const float qv = sQ[row * 132 + k];
        float4 s = *(const float4*)(Sg + (size_t)k * 128);
        a0 += qv * s.x; a1 += qv * s.y; a2 += qv * s.z; a3 += qv * s.w;
    }
#pragma unroll 8
    for (int tp = 0; tp < 32; ++tp) {
        const float sc = sSc[row * 36 + tp];
        float4 v = *(const float4*)&sVs[tp * 36 + c4 * 4];
        a0 += sc * v.x; a1 += sc * v.y; a2 += sc * v.z; a3 += sc * v.w;
    }
    __syncthreads();   // sDen visible

    const float dv = sDen[row];
    *(float4*)(out + ((size_t)cb * 32 + row) * 128 + ch * 32 + c4 * 4) =
        make_float4(a0 / dv, a1 / dv, a2 / dv, a3 / dv);
}

// ---------------------------------------------------------------------------
extern "C" void kernel_launch(void* const* d_in, const int* in_sizes, int n_in,
                              void* d_out, int out_size, void* d_ws, size_t ws_size,
                              hipStream_t stream)
{
    const float* x    = (const float*)d_in[0];   // (B,T,D)
    const float* W    = (const float*)d_in[1];   // (3D, D)
    const float* bias = (const float*)d_in[2];   // (3D,)
    float* out = (float*)d_out;                  // (B,T,D)

    float* ws  = (float*)d_ws;
    float* qb  = ws;                       // 1,048,576 floats
    float* kb  = ws + 1048576;             // 1,048,576
    float* vb  = ws + 2097152;             // 1,048,576
    float* kvb = ws + 3145728;             // 4,194,304
    float* ksb = ws + 7340032;             // 32,768
    float* scb = ws + 7372800;             // 262,144
    float* rsb = ws + 7634944;             // 8,192
    float* Wt  = ws + 7643136;             // 49,152

    wt_kernel<<<48, 256, 0, stream>>>(W, Wt);
    qkv_kernel<<<NROW / 16, 192, 0, stream>>>(x, Wt, bias, qb, kb, vb);
    cs_kernel<<<768, 256, 0, stream>>>(qb, kb, vb, kvb, ksb, scb, rsb);
    prefix_kernel<<<258, 256, 0, stream>>>(kvb, ksb);
    out_kernel<<<1024, 256, 0, stream>>>(qb, vb, kvb, ksb, scb, rsb, out);
}

// Round 7
// 121.317 us; speedup vs baseline: 1.7325x; 1.0985x over previous
//
#include <hip/hip_runtime.h>
#include <math.h>

#define NCn 64            // chunks per batch
#define NCHUNK 256        // total chunks (B=4)
#define NROW 8192         // B*T

__device__ __forceinline__ float elu1(float v) {
    return (v > 0.f) ? v + 1.f : expf(v);
}

// ---------------------------------------------------------------------------
// Kernel A: qkv = x @ W^T + b ; q,k <- elu+1 ; split into q,k,v buffers
// grid (128 M-tiles, 6 col-tiles) x 256 threads; 64x64 tile, 4x4 micro-tile.
// Thread covers rows r0..r0+3 and STRIDED cols (tx + 16*ci): W-tile LDS
// reads are consecutive-row (stride 36 floats -> 2-way banks, free);
// x-tile reads are broadcast. ~70 VGPR -> no spill.
// ---------------------------------------------------------------------------
__global__ __launch_bounds__(256) void qkv_kernel(
    const float* __restrict__ x, const float* __restrict__ W,
    const float* __restrict__ bias,
    float* __restrict__ qb, float* __restrict__ kb, float* __restrict__ vb)
{
    __shared__ __align__(16) float sX[64 * 36];
    __shared__ __align__(16) float sW[64 * 36];
    const int tid = threadIdx.x;
    const int m0 = blockIdx.x * 64;
    const int cbase = blockIdx.y * 64;

    const int ty = tid >> 4, tx = tid & 15;
    const int r0 = ty * 4;

    float acc[4][4];
#pragma unroll
    for (int r = 0; r < 4; ++r)
#pragma unroll
        for (int c = 0; c < 4; ++c) acc[r][c] = 0.f;

    for (int kc = 0; kc < 4; ++kc) {
        __syncthreads();   // previous-iter readers done
        {
            int idx = tid;
#pragma unroll
            for (int i = 0; i < 2; ++i, idx += 256) {
                const int row = idx >> 3, f = idx & 7;
                *(float4*)&sX[row * 36 + f * 4] =
                    *(const float4*)(x + (size_t)(m0 + row) * 128 + kc * 32 + f * 4);
                *(float4*)&sW[row * 36 + f * 4] =
                    *(const float4*)(W + (size_t)(cbase + row) * 128 + kc * 32 + f * 4);
            }
        }
        __syncthreads();

#pragma unroll
        for (int k4 = 0; k4 < 8; ++k4) {
            float4 xr[4], wr[4];
#pragma unroll
            for (int r = 0; r < 4; ++r)
                xr[r] = *(const float4*)&sX[(r0 + r) * 36 + k4 * 4];
#pragma unroll
            for (int c = 0; c < 4; ++c)
                wr[c] = *(const float4*)&sW[(tx + 16 * c) * 36 + k4 * 4];
#pragma unroll
            for (int r = 0; r < 4; ++r)
#pragma unroll
                for (int c = 0; c < 4; ++c)
                    acc[r][c] += xr[r].x * wr[c].x + xr[r].y * wr[c].y
                               + xr[r].z * wr[c].z + xr[r].w * wr[c].w;
        }
    }

    // epilogue: cols gcol = cbase + tx + 16*ci ; block's 64-col slice is
    // entirely within one of q/k/v (cbase multiple of 64).
    float* dst; int coff; bool act;
    if (cbase < 128)      { dst = qb; coff = cbase;       act = true;  }
    else if (cbase < 256) { dst = kb; coff = cbase - 128; act = true;  }
    else                  { dst = vb; coff = cbase - 256; act = false; }

    float bb[4];
#pragma unroll
    for (int c = 0; c < 4; ++c) bb[c] = bias[cbase + tx + 16 * c];

#pragma unroll
    for (int r = 0; r < 4; ++r) {
        float* drow = dst + (size_t)(m0 + r0 + r) * 128 + coff + tx;
#pragma unroll
        for (int c = 0; c < 4; ++c) {
            float o = acc[r][c] + bb[c];
            if (act) o = elu1(o);
            drow[16 * c] = o;
        }
    }
}

// ---------------------------------------------------------------------------
// Kernel CS: grid 768 x 256, LDS 38.4 KB -> 3 blocks/CU. (unchanged from R5)
//  blocks [0,512): half-K^T V. cb = b>>1, jh = b&1: 128 x 64 of kvb[cb].
//  blocks [512,768): scores. cb = b-512: causal QK^T (32x32) -> scb, sSc;
//                    rowsum -> rsb; colsum(K) -> ksb.
// ---------------------------------------------------------------------------
__global__ __launch_bounds__(256) void cs_kernel(
    const float* __restrict__ qb, const float* __restrict__ kb,
    const float* __restrict__ vb,
    float* __restrict__ kvb, float* __restrict__ ksb,
    float* __restrict__ scb, float* __restrict__ rsb)
{
    __shared__ __align__(16) float smem[9600];   // 38.4 KB
    const int tid = threadIdx.x;
    const int b = blockIdx.x;

    if (b < 512) {
        const int cb = b >> 1, jh = b & 1;
        float* sK  = smem;          // [32][132]
        float* sVh = smem + 4224;   // [32][68]
        {
            const float4* kg = (const float4*)(kb + (size_t)cb * 4096);
#pragma unroll
            for (int i = 0; i < 4; ++i) {
                int idx = tid + i * 256;
                int r = idx >> 5, c4 = idx & 31;
                *(float4*)&sK[r * 132 + c4 * 4] = kg[idx];
            }
            const float* vg = vb + (size_t)cb * 4096 + jh * 64;
#pragma unroll
            for (int i = 0; i < 2; ++i) {
                int idx = tid + i * 256;
                int r = idx >> 4, c4 = idx & 15;
                *(float4*)&sVh[r * 68 + c4 * 4] = *(const float4*)(vg + r * 128 + c4 * 4);
            }
        }
        __syncthreads();

        const int i0 = (tid >> 4) * 8;
        const int j0 = (tid & 15) * 4;
        float acc[8][4];
#pragma unroll
        for (int a = 0; a < 8; ++a)
#pragma unroll
            for (int c = 0; c < 4; ++c) acc[a][c] = 0.f;

#pragma unroll 2
        for (int t = 0; t < 32; ++t) {
            float4 ka  = *(const float4*)&sK[t * 132 + i0];
            float4 kb4 = *(const float4*)&sK[t * 132 + i0 + 4];
            float4 vv  = *(const float4*)&sVh[t * 68 + j0];
            float kk[8] = {ka.x, ka.y, ka.z, ka.w, kb4.x, kb4.y, kb4.z, kb4.w};
#pragma unroll
            for (int a = 0; a < 8; ++a) {
                acc[a][0] += kk[a] * vv.x;
                acc[a][1] += kk[a] * vv.y;
                acc[a][2] += kk[a] * vv.z;
                acc[a][3] += kk[a] * vv.w;
            }
        }
        float* outp = kvb + (size_t)cb * 16384 + jh * 64;
#pragma unroll
        for (int a = 0; a < 8; ++a)
            *(float4*)&outp[(i0 + a) * 128 + j0] =
                make_float4(acc[a][0], acc[a][1], acc[a][2], acc[a][3]);
    } else {
        const int cb = b - 512;
        float* sQ  = smem;          // [32][132]
        float* sK2 = smem + 4224;   // [32][132]
        float* sSc = smem + 8448;   // [32][36]
        {
            const float4* qg = (const float4*)(qb + (size_t)cb * 4096);
            const float4* kg = (const float4*)(kb + (size_t)cb * 4096);
#pragma unroll
            for (int i = 0; i < 4; ++i) {
                int idx = tid + i * 256;
                int r = idx >> 5, c4 = idx & 31;
                *(float4*)&sQ[r * 132 + c4 * 4]  = qg[idx];
                *(float4*)&sK2[r * 132 + c4 * 4] = kg[idx];
            }
        }
        __syncthreads();

        const int ta  = tid >> 3;
        const int tp0 = (tid & 7) * 4;
        float d[4] = {0.f, 0.f, 0.f, 0.f};
#pragma unroll 4
        for (int k4 = 0; k4 < 32; ++k4) {
            float4 qa = *(const float4*)&sQ[ta * 132 + k4 * 4];
#pragma unroll
            for (int u = 0; u < 4; ++u) {
                float4 kv = *(const float4*)&sK2[(tp0 + u) * 132 + k4 * 4];
                d[u] += qa.x * kv.x + qa.y * kv.y + qa.z * kv.z + qa.w * kv.w;
            }
        }
        float4 m;
        m.x = (tp0 + 0 <= ta) ? d[0] : 0.f;
        m.y = (tp0 + 1 <= ta) ? d[1] : 0.f;
        m.z = (tp0 + 2 <= ta) ? d[2] : 0.f;
        m.w = (tp0 + 3 <= ta) ? d[3] : 0.f;
        *(float4*)&sSc[ta * 36 + tp0] = m;
        *(float4*)(scb + (size_t)cb * 1024 + ta * 32 + tp0) = m;
        __syncthreads();

        if (tid < 32) {
            float s = 0.f;
#pragma unroll
            for (int tp = 0; tp < 32; ++tp) s += sSc[tid * 36 + tp];
            rsb[cb * 32 + tid] = s;
        } else if (tid >= 64 && tid < 192) {
            const int i = tid - 64;
            float s = 0.f;
#pragma unroll
            for (int t = 0; t < 32; ++t) s += sK2[t * 132 + i];
            ksb[cb * 128 + i] = s;
        }
    }
}

// ---------------------------------------------------------------------------
// Kernel C: in-place exclusive prefix over 64 chunks per batch (kvb, ksb).
// (unchanged from R5)
// ---------------------------------------------------------------------------
__global__ __launch_bounds__(256) void prefix_kernel(
    float* __restrict__ kvb, float* __restrict__ ksb)
{
    const int tid = threadIdx.x;
    if (blockIdx.x < 256) {
        const int L = blockIdx.x * 256 + tid;
        const int b = L >> 14, ij = L & 16383;
        float* p = kvb + (size_t)b * NCn * 16384 + ij;
        float run = 0.f;
        for (int g = 0; g < 4; ++g) {
            float buf[16];
#pragma unroll
            for (int j = 0; j < 16; ++j) buf[j] = p[(size_t)(g * 16 + j) * 16384];
#pragma unroll
            for (int j = 0; j < 16; ++j) {
                p[(size_t)(g * 16 + j) * 16384] = run;
                run += buf[j];
            }
        }
    } else {
        const int L = (blockIdx.x - 256) * 256 + tid;
        const int b = L >> 7, i = L & 127;
        float* p = ksb + (size_t)b * NCn * 128 + i;
        float run = 0.f;
        for (int g = 0; g < 4; ++g) {
            float buf[16];
#pragma unroll
            for (int j = 0; j < 16; ++j) buf[j] = p[(size_t)(g * 16 + j) * 128];
#pragma unroll
            for (int j = 0; j < 16; ++j) {
                p[(size_t)(g * 16 + j) * 128] = run;
                run += buf[j];
            }
        }
    }
}

// ---------------------------------------------------------------------------
// Kernel D: out = (Q @ S_prefix + Sc @ V) / den   (unchanged from R5)
// grid 1024 x 256 (4 col-blocks per chunk), LDS 22.8 KB -> 4 blocks/CU.
// ---------------------------------------------------------------------------
__global__ __launch_bounds__(256) void out_kernel(
    const float* __restrict__ qb, const float* __restrict__ vb,
    const float* __restrict__ kvb, const float* __restrict__ ksb,
    const float* __restrict__ scb, const float* __restrict__ rsb,
    float* __restrict__ out)
{
    __shared__ __align__(16) float sQ[32 * 132];
    __shared__ __align__(16) float sVs[32 * 36];
    __shared__ __align__(16) float sSc[32 * 36];
    __shared__ __align__(16) float sKp[128];
    __shared__ float sDen[32];

    const int tid = threadIdx.x;
    const int cb = blockIdx.x >> 2;
    const int ch = blockIdx.x & 3;

    {
        const float4* qg = (const float4*)(qb + (size_t)cb * 4096);
#pragma unroll
        for (int i = 0; i < 4; ++i) {
            int idx = tid + i * 256;
            int r = idx >> 5, c4 = idx & 31;
            *(float4*)&sQ[r * 132 + c4 * 4] = qg[idx];
        }
        {
            int r = tid >> 3, c4 = tid & 7;
            *(float4*)&sVs[r * 36 + c4 * 4] =
                *(const float4*)(vb + (size_t)cb * 4096 + r * 128 + ch * 32 + c4 * 4);
            *(float4*)&sSc[r * 36 + c4 * 4] =
                *(const float4*)(scb + (size_t)cb * 1024 + tid * 4);
        }
        if (tid < 128) sKp[tid] = ksb[cb * 128 + tid];
    }
    __syncthreads();

    if (tid < 32) {
        float d = 0.f;
#pragma unroll
        for (int k4 = 0; k4 < 32; ++k4) {
            float4 a  = *(const float4*)&sQ[tid * 132 + k4 * 4];
            float4 b2 = *(const float4*)&sKp[k4 * 4];
            d += a.x * b2.x + a.y * b2.y + a.z * b2.z + a.w * b2.w;
        }
        sDen[tid] = d + rsb[cb * 32 + tid] + 1e-6f;
    }

    const int row = tid >> 3;
    const int c4  = tid & 7;
    const float* Sg = kvb + (size_t)cb * 16384 + ch * 32 + c4 * 4;

    float a0 = 0.f, a1 = 0.f, a2 = 0.f, a3 = 0.f;
#pragma unroll 8
    for (int k = 0; k < 128; ++k) {
        const float qv = sQ[row * 132 + k];
        float4 s = *(const float4*)(Sg + (size_t)k * 128);
        a0 += qv * s.x; a1 += qv * s.y; a2 += qv * s.z; a3 += qv * s.w;
    }
#pragma unroll 8
    for (int tp = 0; tp < 32; ++tp) {
        const float sc = sSc[row * 36 + tp];
        float4 v = *(const float4*)&sVs[tp * 36 + c4 * 4];
        a0 += sc * v.x; a1 += sc * v.y; a2 += sc * v.z; a3 += sc * v.w;
    }
    __syncthreads();

    const float dv = sDen[row];
    *(float4*)(out + ((size_t)cb * 32 + row) * 128 + ch * 32 + c4 * 4) =
        make_float4(a0 / dv, a1 / dv, a2 / dv, a3 / dv);
}

// ---------------------------------------------------------------------------
extern "C" void kernel_launch(void* const* d_in, const int* in_sizes, int n_in,
                              void* d_out, int out_size, void* d_ws, size_t ws_size,
                              hipStream_t stream)
{
    const float* x    = (const float*)d_in[0];   // (B,T,D)
    const float* W    = (const float*)d_in[1];   // (3D, D)
    const float* bias = (const float*)d_in[2];   // (3D,)
    float* out = (float*)d_out;                  // (B,T,D)

    float* ws  = (float*)d_ws;
    float* qb  = ws;                       // 1,048,576 floats
    float* kb  = ws + 1048576;             // 1,048,576
    float* vb  = ws + 2097152;             // 1,048,576
    float* kvb = ws + 3145728;             // 4,194,304
    float* ksb = ws + 7340032;             // 32,768
    float* scb = ws + 7372800;             // 262,144
    float* rsb = ws + 7634944;             // 8,192

    qkv_kernel<<<dim3(128, 6), 256, 0, stream>>>(x, W, bias, qb, kb, vb);
    cs_kernel<<<768, 256, 0, stream>>>(qb, kb, vb, kvb, ksb, scb, rsb);
    prefix_kernel<<<258, 256, 0, stream>>>(kvb, ksb);
    out_kernel<<<1024, 256, 0, stream>>>(qb, vb, kvb, ksb, scb, rsb, out);
}